// Round 15
// baseline (366.152 us; speedup 1.0000x reference)
//
#include <hip/hip_runtime.h>
#include <hip/hip_bf16.h>
#include <cstdint>
#include <cstddef>
#include <cstring>

typedef unsigned short u16;
typedef unsigned char u8;
typedef __attribute__((ext_vector_type(8))) short short8;   // 8 x bf16 (4 VGPRs)
typedef __attribute__((ext_vector_type(4))) float f32x4;    // MFMA C/D

#define B_    4
#define T_    2048
#define D_    1024
#define H_    16
#define DK_   64
// SCALE * log2(e): scores exponentiate via 2^x (single v_exp_f32)
#define QSCALE_ 0.18033688011112042f

__device__ __forceinline__ float bf2f(u16 u) {
    unsigned int x = ((unsigned int)u) << 16;
    float f; __builtin_memcpy(&f, &x, 4); return f;
}
__device__ __forceinline__ u16 f2bf(float f) {
    unsigned int x; __builtin_memcpy(&x, &f, 4);
    x += 0x7fffu + ((x >> 16) & 1u);   // round-to-nearest-even
    return (u16)(x >> 16);
}
// pack two floats to bf16x2 (round-half-up): 2 adds + 1 v_perm_b32.
__device__ __forceinline__ unsigned pack_bf16_hu(float lo, float hi) {
    unsigned a, b;
    __builtin_memcpy(&a, &lo, 4);
    __builtin_memcpy(&b, &hi, 4);
    return __builtin_amdgcn_perm(b + 0x8000u, a + 0x8000u, 0x07060302u);
}

// ---------------- Fused prep+convert+LN mega-kernel ----------------
__device__ __forceinline__ int sniff_flag(const u16* __restrict__ x, int tid) {
    __shared__ int sc[4];
    int cnt = 0;
    for (int i = tid; i < 512; i += 256) {
        int e = (x[8 * i] >> 7) & 0xFF;     // low u16 of f32 / real bf16
        if (e > 137 || (e >= 1 && e < 97)) cnt++;
    }
    for (int o = 1; o < 64; o <<= 1) cnt += __shfl_xor(cnt, o);
    if ((tid & 63) == 0) sc[tid >> 6] = cnt;
    __syncthreads();
    return (sc[0] + sc[1] + sc[2] + sc[3] > 128) ? 1 : 0;   // fp32 ~83% hit rate
}

__global__ __launch_bounds__(256) void mega_prep(
    const u16* __restrict__ x, const u8* __restrict__ m,
    const void* wq, const void* wk, const void* wv, const void* wo,
    const void* bq, const void* bk, const void* bv, const void* bo,
    const void* lng, const void* lnb,
    u16* __restrict__ wqc, u16* __restrict__ wkc,
    u16* __restrict__ wvc, u16* __restrict__ woc,
    u16* __restrict__ vecs, float* __restrict__ msk, int* flag,
    u16* __restrict__ xn)
{
    int tid = threadIdx.x;
    int f = sniff_flag(x, tid);
    int id = blockIdx.x;

    if (id < 4096) {
        // ---- weight canonicalize: 4 x [1024,1024] -> bf16 ----
        int mat = id >> 10;
        const void* s = (mat == 0) ? wq : (mat == 1) ? wk : (mat == 2) ? wv : wo;
        u16* d = (mat == 0) ? wqc : (mat == 1) ? wkc : (mat == 2) ? wvc : woc;
        int i4 = (id & 1023) * 256 + tid;
        if (f) {
            float4 v = ((const float4*)s)[i4];
            ushort4 o; o.x = f2bf(v.x); o.y = f2bf(v.y); o.z = f2bf(v.z); o.w = f2bf(v.w);
            ((ushort4*)d)[i4] = o;
        } else {
            ((ushort4*)d)[i4] = ((const ushort4*)s)[i4];
        }
    } else if (id < 12288) {
        // ---- LayerNorm row ----
        __shared__ float rs[4], rq[4];
        int row = id - 4096;
        int t = tid;
        float v[4];
        if (f) {
            float4 f4 = ((const float4*)x)[(size_t)row * 256 + t];
            v[0] = f4.x; v[1] = f4.y; v[2] = f4.z; v[3] = f4.w;
        } else {
            ushort4 uv = ((const ushort4*)x)[(size_t)row * 256 + t];
            v[0] = bf2f(uv.x); v[1] = bf2f(uv.y); v[2] = bf2f(uv.z); v[3] = bf2f(uv.w);
        }
        float s = v[0] + v[1] + v[2] + v[3];
        float q = v[0]*v[0] + v[1]*v[1] + v[2]*v[2] + v[3]*v[3];
        for (int o = 1; o < 64; o <<= 1) { s += __shfl_xor(s, o); q += __shfl_xor(q, o); }
        int wv_ = t >> 6, ln = t & 63;
        if (ln == 0) { rs[wv_] = s; rq[wv_] = q; }
        __syncthreads();
        s = rs[0] + rs[1] + rs[2] + rs[3];
        q = rq[0] + rq[1] + rq[2] + rq[3];
        float mu   = s * (1.0f / D_);
        float var  = q * (1.0f / D_) - mu * mu;
        float rstd = rsqrtf(var + 1e-5f);
        u16 o4[4];
        for (int i = 0; i < 4; i++) {
            float gv, bv_;
            if (f) { gv = ((const float*)lng)[t*4 + i]; bv_ = ((const float*)lnb)[t*4 + i]; }
            else   { gv = bf2f(((const u16*)lng)[t*4 + i]); bv_ = bf2f(((const u16*)lnb)[t*4 + i]); }
            o4[i] = f2bf((v[i] - mu) * rstd * gv + bv_);
        }
        ushort4 ov; ov.x = o4[0]; ov.y = o4[1]; ov.z = o4[2]; ov.w = o4[3];
        *(ushort4*)(xn + (size_t)row * D_ + t * 4) = ov;
    } else {
        // ---- mask bias (+ vecs + flag on block 12288) ----
        __shared__ int sb[4];
        int k = id - 12288;                  // 0..7
        int bits = 0;
        for (int i = tid; i < B_ * T_; i += 256)
            if (m[i]) bits |= (i & 7);
        for (int o = 1; o < 64; o <<= 1) bits |= __shfl_xor(bits, o);
        if ((tid & 63) == 0) sb[tid >> 6] = bits;
        __syncthreads();
        bits = sb[0] | sb[1] | sb[2] | sb[3];
        int stride = (bits & 1) ? 1 : (bits & 2) ? 2 : (bits & 4) ? 4 : 8;
        for (int i = tid; i < 1024; i += 256) {
            int idx = k * 1024 + i;
            msk[idx] = m[(size_t)idx * stride] ? -200.f : 0.f;
        }
        if (k == 0) {
            if (tid == 0) *flag = f;
            const void* ss[6] = {bq, bk, bv, bo, lng, lnb};
            for (int t = 0; t < 6; t++) {
                const void* s = ss[t];
                for (int i = tid; i < 1024; i += 256)
                    vecs[t * 1024 + i] = f ? f2bf(((const float*)s)[i]) : ((const u16*)s)[i];
            }
        }
    }
}

// ------------- GEMM C = A[8192,1024] . W[1024,1024]^T + bias, *scale -------------
// R11: for Q/K/final slices the MFMA operands are SWAPPED (mfma(b,a,acc) —
// fragments are layout-compatible both ways). Output is then C^T-mapped:
// each lane holds 4 CONSECUTIVE C-columns at a fixed row -> epilogue stores
// become 16x ushort4/float4 instead of 64 scalar u16 (G13), and per-head
// l2norm is lane-local over 16 vals + 2 shfls (was 64 shfls). V slice keeps
// the original order (its transposed store already packs 4 rows -> ushort4).
// Grid (64,8,z), x = row tile: all 24 blocks sharing an A-row-tile land on
// one XCD (T1).
__global__ __launch_bounds__(256) void gemm_bt(
    const u16* __restrict__ A,
    const u16* __restrict__ W0, const u16* __restrict__ W1, const u16* __restrict__ W2,
    const u16* __restrict__ bias_all, int bias_idx0,
    u16* __restrict__ C0, u16* __restrict__ C1, u16* __restrict__ C2,
    float scale, const int* __restrict__ flag, int use_flag, int qkv_mode)
{
    const int K = 1024, N = 1024;
    const u16* W; const u16* bias; u16* C;
    if (blockIdx.z == 0)      { W = W0; bias = bias_all + (size_t)bias_idx0 * 1024;       C = C0; }
    else if (blockIdx.z == 1) { W = W1; bias = bias_all + (size_t)(bias_idx0 + 1) * 1024; C = C1; }
    else                      { W = W2; bias = bias_all + (size_t)(bias_idx0 + 2) * 1024; C = C2; }

    __shared__ u16 As[128 * 32];   // no pad: required by global_load_lds layout
    __shared__ u16 Bs[128 * 32];

    int tid  = threadIdx.x;
    int wave = tid >> 6, lane = tid & 63;
    int wm = wave >> 1, wn = wave & 1;
    int quad = lane >> 4, l16 = lane & 15;
    int bm = blockIdx.x * 128, bn = blockIdx.y * 128;   // x = row tile (XCD locality)

    int do_swap = !(qkv_mode && blockIdx.z == 2);       // all but V slice

    f32x4 acc[4][4];
    const f32x4 fz = {0.f, 0.f, 0.f, 0.f};
    for (int i = 0; i < 4; i++) for (int j = 0; j < 4; j++) acc[i][j] = fz;

    int srow = lane >> 2;
    int scol = (lane & 3) * 8;
    const u16* gA0 = A + (size_t)(bm + wave * 32 + srow) * K + scol;
    const u16* gB0 = W + (size_t)(bn + wave * 32 + srow) * K + scol;

    for (int k0 = 0; k0 < K; k0 += 32) {
        for (int i = 0; i < 2; i++) {
            __builtin_amdgcn_global_load_lds(
                (const __attribute__((address_space(1))) void*)(gA0 + (size_t)i * 16 * K + k0),
                (__attribute__((address_space(3))) void*)(As + (wave * 32 + i * 16) * 32),
                16, 0, 0);
            __builtin_amdgcn_global_load_lds(
                (const __attribute__((address_space(1))) void*)(gB0 + (size_t)i * 16 * K + k0),
                (__attribute__((address_space(3))) void*)(Bs + (wave * 32 + i * 16) * 32),
                16, 0, 0);
        }
        __syncthreads();
        short8 a[4], b[4];
        for (int i = 0; i < 4; i++)
            a[i] = *(const short8*)(As + (wm * 64 + i * 16 + l16) * 32 + quad * 8);
        for (int j = 0; j < 4; j++)
            b[j] = *(const short8*)(Bs + (wn * 64 + j * 16 + l16) * 32 + quad * 8);
        if (do_swap) {
            for (int i = 0; i < 4; i++)
                for (int j = 0; j < 4; j++)
                    acc[i][j] = __builtin_amdgcn_mfma_f32_16x16x32_bf16(b[j], a[i], acc[i][j], 0, 0, 0);
        } else {
            for (int i = 0; i < 4; i++)
                for (int j = 0; j < 4; j++)
                    acc[i][j] = __builtin_amdgcn_mfma_f32_16x16x32_bf16(a[i], b[j], acc[i][j], 0, 0, 0);
        }
        __syncthreads();
    }

    if (qkv_mode && blockIdx.z == 2) {
        // V (non-swapped): transposed store Vt[((b*16+h)*64+d)*2048 + t]
        for (int j = 0; j < 4; j++) {
            int col = bn + wn * 64 + j * 16 + l16;
            int h = col >> 6, d = col & 63;
            float bi = bf2f(bias[col]);
            for (int i = 0; i < 4; i++) {
                int row0 = bm + wm * 64 + i * 16 + quad * 4;
                int bq = row0 >> 11, t0 = row0 & 2047;
                ushort4 pk;
                pk.x = f2bf(acc[i][j][0] + bi); pk.y = f2bf(acc[i][j][1] + bi);
                pk.z = f2bf(acc[i][j][2] + bi); pk.w = f2bf(acc[i][j][3] + bi);
                *(ushort4*)(C + ((size_t)((bq * 16 + h) * 64 + d)) * 2048 + t0) = pk;
            }
        }
        return;
    }

    // swapped epilogues: lane holds cols bn+wn*64+j*16+quad*4 .. +3 at row
    // bm+wm*64+i*16+l16. Bias hoisted: 4 ushort4 loads.
    float bi[4][4];
    for (int j = 0; j < 4; j++) {
        ushort4 b4 = *(const ushort4*)(bias + bn + wn * 64 + j * 16 + quad * 4);
        bi[j][0] = bf2f(b4.x); bi[j][1] = bf2f(b4.y);
        bi[j][2] = bf2f(b4.z); bi[j][3] = bf2f(b4.w);
    }

    if (qkv_mode) {
        // Q/K: bias + per-head l2norm (+QSCALE for Q); head = the wave's 64 cols
        float sc2 = (blockIdx.z == 0) ? QSCALE_ : 1.0f;
        for (int i = 0; i < 4; i++) {
            int row = bm + wm * 64 + i * 16 + l16;
            float v[4][4]; float s = 0.f;
            for (int j = 0; j < 4; j++)
                for (int r = 0; r < 4; r++) {
                    float val = acc[i][j][r] + bi[j][r];
                    v[j][r] = val; s += val * val;
                }
            s += __shfl_xor(s, 16);
            s += __shfl_xor(s, 32);
            float scl = sc2 / fmaxf(sqrtf(s), 1e-8f);
            for (int j = 0; j < 4; j++) {
                ushort4 pk;
                pk.x = f2bf(v[j][0] * scl); pk.y = f2bf(v[j][1] * scl);
                pk.z = f2bf(v[j][2] * scl); pk.w = f2bf(v[j][3] * scl);
                *(ushort4*)(C + (size_t)row * N + bn + wn * 64 + j * 16 + quad * 4) = pk;
            }
        }
        return;
    }

    int f32out = use_flag ? *flag : 0;
    for (int i = 0; i < 4; i++) {
        int row = bm + wm * 64 + i * 16 + l16;
        for (int j = 0; j < 4; j++) {
            int colb = bn + wn * 64 + j * 16 + quad * 4;
            float o0 = (acc[i][j][0] + bi[j][0]) * scale;
            float o1 = (acc[i][j][1] + bi[j][1]) * scale;
            float o2 = (acc[i][j][2] + bi[j][2]) * scale;
            float o3 = (acc[i][j][3] + bi[j][3]) * scale;
            if (f32out) {
                float4 f4 = {o0, o1, o2, o3};
                *(float4*)(&((float*)C)[(size_t)row * N + colb]) = f4;
            } else {
                ushort4 pk;
                pk.x = f2bf(o0); pk.y = f2bf(o1); pk.z = f2bf(o2); pk.w = f2bf(o3);
                *(ushort4*)(C + (size_t)row * N + colb) = pk;
            }
        }
    }
}

// ---------------- Flash-style attention v12 ----------------
// v11 (123.5us, VALU 65% + MFMA 24%) + rowsum via all-ones MFMA: one extra
// mfma(ones, pb[g], rs) per (j2,g) gives every lane the full 32-key row-sum
// for its q (A=1s => D[.][q] = sum_k P[q][k], replicated across rows) --
// deletes 24 VALU adds/tile + both epilogue shfls, and makes num/denom
// consistently bf16-rounded (errors cancel). MFMA pipe has 76% headroom.
__global__ __launch_bounds__(256, 4) void attn_kernel(
    const u16* __restrict__ Q, const u16* __restrict__ Kg,
    const u16* __restrict__ Vt, const float* __restrict__ msk,
    u16* __restrict__ Oout)
{
    __shared__ __align__(16) u16 Ks[2 * 64 * 64];   // [buf][rho(key)][dk], chunk-swizzled
    __shared__ __align__(16) u16 VTs[2 * 64 * 64];  // [buf][dk][key],      chunk-swizzled

    int tid  = threadIdx.x;
    int wave = tid >> 6, lane = tid & 63;
    int quad = lane >> 4, l16 = lane & 15;
    int q0 = blockIdx.y * 128;                    // XCD locality: x = bh
    int b  = blockIdx.x >> 4, h = blockIdx.x & 15;
    const size_t base  = (size_t)b * T_ * D_ + h * DK_;
    const size_t vbase = (size_t)((b * 16 + h) * 64) * T_;

    // Q fragments for two 16-query groups (pre-normalized, pre-scaled)
    short8 qa[2][2];
    for (int g = 0; g < 2; g++) {
        const u16* qrow = Q + base + (size_t)(q0 + wave * 32 + g * 16 + l16) * D_;
        qa[g][0] = *(const short8*)(qrow + quad * 8);
        qa[g][1] = *(const short8*)(qrow + 32 + quad * 8);
    }

    const float* mq = msk + b * T_ + quad * 8;   // + kt + j2*32 + s*4

    // gload_lds staging geometry: lane l -> (row rL = w*8+p*32+(l>>3), chunk l&7)
    int rL0 = wave * 8 + (lane >> 3);
    int rL1 = rL0 + 32;
    int c   = lane & 7;
    int k0i = (rL0 & 32) + ((rL0 >> 2) & 3) * 8 + ((rL0 >> 4) & 1) * 4 + (rL0 & 3);
    int k1i = (rL1 & 32) + ((rL1 >> 2) & 3) * 8 + ((rL1 >> 4) & 1) * 4 + (rL1 & 3);
    const u16* kgs0 = Kg + base + (size_t)k0i * D_ + (c ^ (rL0 & 7)) * 8;
    const u16* kgs1 = Kg + base + (size_t)k1i * D_ + (c ^ (rL1 & 7)) * 8;
    const u16* vgs0 = Vt + vbase + (size_t)rL0 * T_ + (c ^ (rL0 & 7)) * 8;
    const u16* vgs1 = Vt + vbase + (size_t)rL1 * T_ + (c ^ (rL1 & 7)) * 8;
    u16* kd0 = Ks  + (wave * 8) * 64;            // wave-uniform LDS bases
    u16* kd1 = Ks  + (wave * 8 + 32) * 64;
    u16* vd0 = VTs + (wave * 8) * 64;
    u16* vd1 = VTs + (wave * 8 + 32) * 64;

#define STAGE(BUF, KOFF) do {                                                   \
    __builtin_amdgcn_global_load_lds(                                           \
        (const __attribute__((address_space(1))) void*)(kgs0 + (size_t)(KOFF) * D_), \
        (__attribute__((address_space(3))) void*)(kd0 + (BUF) * 4096), 16, 0, 0); \
    __builtin_amdgcn_global_load_lds(                                           \
        (const __attribute__((address_space(1))) void*)(kgs1 + (size_t)(KOFF) * D_), \
        (__attribute__((address_space(3))) void*)(kd1 + (BUF) * 4096), 16, 0, 0); \
    __builtin_amdgcn_global_load_lds(                                           \
        (const __attribute__((address_space(1))) void*)(vgs0 + (KOFF)),         \
        (__attribute__((address_space(3))) void*)(vd0 + (BUF) * 4096), 16, 0, 0); \
    __builtin_amdgcn_global_load_lds(                                           \
        (const __attribute__((address_space(1))) void*)(vgs1 + (KOFF)),         \
        (__attribute__((address_space(3))) void*)(vd1 + (BUF) * 4096), 16, 0, 0); \
} while (0)

    // prologue: stage tile 0 into buffer 0
    STAGE(0, 0);
    __syncthreads();

    // per-lane LDS read bases (buffer + subtile offsets fold to immediates)
    const u16* kr_lo = Ks + l16 * 64 + ((quad ^ (l16 & 7)) * 8);        // dk 0..31
    const u16* kr_hi = Ks + l16 * 64 + (((4 + quad) ^ (l16 & 7)) * 8);  // dk 32..63
    const u16* vr0 = VTs + l16 * 64 + ((quad ^ (l16 & 7)) * 8);         // j2=0
    const u16* vr1 = VTs + l16 * 64 + (((4 + quad) ^ (l16 & 7)) * 8);   // j2=1

    f32x4 o_acc[2][4];   // O^T: lane holds d = jd*16+quad*4+r, q = l16
    for (int g = 0; g < 2; g++) for (int j = 0; j < 4; j++) o_acc[g][j] = f32x4{0.f, 0.f, 0.f, 0.f};
    f32x4 rs_acc[2] = {f32x4{0.f,0.f,0.f,0.f}, f32x4{0.f,0.f,0.f,0.f}};
    const short8 vone = {(short)0x3F80, (short)0x3F80, (short)0x3F80, (short)0x3F80,
                         (short)0x3F80, (short)0x3F80, (short)0x3F80, (short)0x3F80};

#define TILE_BODY(CUR, NXT, KT) do {                                            \
    int ktn = ((KT) + 64) & (T_ - 1);                                           \
    STAGE(NXT, ktn);                                                            \
    f32x4 pmt[2][2];                                                            \
    for (int j2 = 0; j2 < 2; j2++)                                              \
        for (int s = 0; s < 2; s++)                                             \
            pmt[j2][s] = *(const f32x4*)(mq + (KT) + j2 * 32 + s * 4);          \
    __builtin_amdgcn_s_setprio(1);                                              \
    for (int j2 = 0; j2 < 2; j2++) {                                            \
        unsigned pw[2][4];                                                      \
        for (int s = 0; s < 2; s++) {                                           \
            short8 kb0 = *(const short8*)(kr_lo + (CUR) * 4096 + (j2 * 32 + s * 16) * 64); \
            short8 kb1 = *(const short8*)(kr_hi + (CUR) * 4096 + (j2 * 32 + s * 16) * 64); \
            for (int g = 0; g < 2; g++) {                                       \
                f32x4 s4 = __builtin_amdgcn_mfma_f32_16x16x32_bf16(kb0, qa[g][0], pmt[j2][s], 0, 0, 0); \
                s4       = __builtin_amdgcn_mfma_f32_16x16x32_bf16(kb1, qa[g][1], s4, 0, 0, 0); \
                float p0 = __builtin_exp2f(s4[0]);                              \
                float p1 = __builtin_exp2f(s4[1]);                              \
                float p2 = __builtin_exp2f(s4[2]);                              \
                float p3 = __builtin_exp2f(s4[3]);                              \
                pw[g][s * 2]     = pack_bf16_hu(p0, p1);                        \
                pw[g][s * 2 + 1] = pack_bf16_hu(p2, p3);                        \
            }                                                                   \
        }                                                                       \
        short8 pb[2];                                                           \
        __builtin_memcpy(&pb[0], &pw[0][0], 16);                                \
        __builtin_memcpy(&pb[1], &pw[1][0], 16);                                \
        rs_acc[0] = __builtin_amdgcn_mfma_f32_16x16x32_bf16(vone, pb[0], rs_acc[0], 0, 0, 0); \
        rs_acc[1] = __builtin_amdgcn_mfma_f32_16x16x32_bf16(vone, pb[1], rs_acc[1], 0, 0, 0); \
        const u16* vr = (j2 ? vr1 : vr0) + (CUR) * 4096;                        \
        for (int jd = 0; jd < 4; jd++) {                                        \
            short8 vv = *(const short8*)(vr + jd * 16 * 64);                    \
            o_acc[0][jd] = __builtin_amdgcn_mfma_f32_16x16x32_bf16(vv, pb[0], o_acc[0][jd], 0, 0, 0); \
            o_acc[1][jd] = __builtin_amdgcn_mfma_f32_16x16x32_bf16(vv, pb[1], o_acc[1][jd], 0, 0, 0); \
        }                                                                       \
    }                                                                           \
    __builtin_amdgcn_s_setprio(0);                                              \
    __syncthreads();                                                            \
} while (0)

    for (int kt = 0; kt < T_; kt += 128) {
        TILE_BODY(0, 1, kt);
        TILE_BODY(1, 0, kt + 64);
    }
#undef TILE_BODY
#undef STAGE

    // epilogue: rs_acc holds the full row-sum replicated (no shfl needed)
    for (int g = 0; g < 2; g++) {
        float inv = 1.0f / fmaxf(rs_acc[g][0], 1e-20f);
        size_t orow = base + (size_t)(q0 + wave * 32 + g * 16 + l16) * D_;
        for (int jd = 0; jd < 4; jd++) {
            ushort4 pk;
            pk.x = f2bf(o_acc[g][jd][0] * inv);
            pk.y = f2bf(o_acc[g][jd][1] * inv);
            pk.z = f2bf(o_acc[g][jd][2] * inv);
            pk.w = f2bf(o_acc[g][jd][3] * inv);
            *(ushort4*)(Oout + orow + jd * 16 + quad * 4) = pk;
        }
    }
}

extern "C" void kernel_launch(void* const* d_in, const int* in_sizes, int n_in,
                              void* d_out, int out_size, void* d_ws, size_t ws_size,
                              hipStream_t stream)
{
    const void* x    = d_in[0];
    const u8*   mask = (const u8*)d_in[1];
    const void* wq   = d_in[2];
    const void* bq   = d_in[3];
    const void* wk   = d_in[4];
    const void* bk   = d_in[5];
    const void* wv   = d_in[6];
    const void* bv   = d_in[7];
    const void* wo   = d_in[8];
    const void* bo   = d_in[9];
    const void* lng  = d_in[10];
    const void* lnb  = d_in[11];

    const size_t NTOK = (size_t)B_ * T_;          // 8192
    u16* xn  = (u16*)d_ws;                        // 16.8 MB; reused as attention output
    u16* Kb  = xn + NTOK * D_;                    // 16.8 MB
    u16* Vtb = Kb + NTOK * D_;                    // 16.8 MB (transposed layout)
    u16* wqc = Vtb + NTOK * D_;                   // 2 MB each
    u16* wkc = wqc + (size_t)D_ * D_;
    u16* wvc = wkc + (size_t)D_ * D_;
    u16* woc = wvc + (size_t)D_ * D_;
    u16* vecs = woc + (size_t)D_ * D_;            // 6 x 1024: bq,bk,bv,bo,ln_g,ln_b
    float* msk = (float*)(vecs + 6 * 1024);       // 32 KB float mask bias (0 / -200)
    int* flag = (int*)(msk + 8192);               // dtype flag: 1 = fp32 inputs
    u16* Qb  = (u16*)d_out;                       // Q in d_out (dead until final GEMM)

    mega_prep<<<dim3(12296), 256, 0, stream>>>(
        (const u16*)x, mask, wq, wk, wv, wo, bq, bk, bv, bo, lng, lnb,
        wqc, wkc, wvc, woc, vecs, msk, flag, xn);
    gemm_bt<<<dim3(64, 8, 3), 256, 0, stream>>>(xn, wqc, wkc, wvc, vecs, 0, Qb, Kb, Vtb, 1.0f, flag, 0, 1);
    attn_kernel<<<dim3(64, 16), 256, 0, stream>>>(Qb, Kb, Vtb, msk, xn);
    gemm_bt<<<dim3(64, 8, 1), 256, 0, stream>>>(xn, woc, woc, woc, vecs, 3, (u16*)d_out, (u16*)d_out, (u16*)d_out, 0.5f, flag, 1, 0);
}

// Round 17
// 340.831 us; speedup vs baseline: 1.0743x; 1.0743x over previous
//
#include <hip/hip_runtime.h>
#include <hip/hip_bf16.h>
#include <cstdint>
#include <cstddef>
#include <cstring>

typedef unsigned short u16;
typedef unsigned char u8;
typedef __attribute__((ext_vector_type(8))) short short8;   // 8 x bf16 (4 VGPRs)
typedef __attribute__((ext_vector_type(4))) float f32x4;    // MFMA C/D

#define B_    4
#define T_    2048
#define D_    1024
#define H_    16
#define DK_   64
// SCALE * log2(e): scores exponentiate via 2^x (single v_exp_f32)
#define QSCALE_ 0.18033688011112042f

__device__ __forceinline__ float bf2f(u16 u) {
    unsigned int x = ((unsigned int)u) << 16;
    float f; __builtin_memcpy(&f, &x, 4); return f;
}
__device__ __forceinline__ u16 f2bf(float f) {
    unsigned int x; __builtin_memcpy(&x, &f, 4);
    x += 0x7fffu + ((x >> 16) & 1u);   // round-to-nearest-even
    return (u16)(x >> 16);
}
// pack two floats to bf16x2 (round-half-up): 2 adds + 1 v_perm_b32.
__device__ __forceinline__ unsigned pack_bf16_hu(float lo, float hi) {
    unsigned a, b;
    __builtin_memcpy(&a, &lo, 4);
    __builtin_memcpy(&b, &hi, 4);
    return __builtin_amdgcn_perm(b + 0x8000u, a + 0x8000u, 0x07060302u);
}

// ---------------- Fused prep+convert+LN mega-kernel ----------------
__device__ __forceinline__ int sniff_flag(const u16* __restrict__ x, int tid) {
    __shared__ int sc[4];
    int cnt = 0;
    for (int i = tid; i < 512; i += 256) {
        int e = (x[8 * i] >> 7) & 0xFF;     // low u16 of f32 / real bf16
        if (e > 137 || (e >= 1 && e < 97)) cnt++;
    }
    for (int o = 1; o < 64; o <<= 1) cnt += __shfl_xor(cnt, o);
    if ((tid & 63) == 0) sc[tid >> 6] = cnt;
    __syncthreads();
    return (sc[0] + sc[1] + sc[2] + sc[3] > 128) ? 1 : 0;   // fp32 ~83% hit rate
}

__global__ __launch_bounds__(256) void mega_prep(
    const u16* __restrict__ x, const u8* __restrict__ m,
    const void* wq, const void* wk, const void* wv, const void* wo,
    const void* bq, const void* bk, const void* bv, const void* bo,
    const void* lng, const void* lnb,
    u16* __restrict__ wqc, u16* __restrict__ wkc,
    u16* __restrict__ wvc, u16* __restrict__ woc,
    u16* __restrict__ vecs, float* __restrict__ msk, int* flag,
    u16* __restrict__ xn)
{
    int tid = threadIdx.x;
    int f = sniff_flag(x, tid);
    int id = blockIdx.x;

    if (id < 4096) {
        // ---- weight canonicalize: 4 x [1024,1024] -> bf16 ----
        int mat = id >> 10;
        const void* s = (mat == 0) ? wq : (mat == 1) ? wk : (mat == 2) ? wv : wo;
        u16* d = (mat == 0) ? wqc : (mat == 1) ? wkc : (mat == 2) ? wvc : woc;
        int i4 = (id & 1023) * 256 + tid;
        if (f) {
            float4 v = ((const float4*)s)[i4];
            ushort4 o; o.x = f2bf(v.x); o.y = f2bf(v.y); o.z = f2bf(v.z); o.w = f2bf(v.w);
            ((ushort4*)d)[i4] = o;
        } else {
            ((ushort4*)d)[i4] = ((const ushort4*)s)[i4];
        }
    } else if (id < 12288) {
        // ---- LayerNorm row ----
        __shared__ float rs[4], rq[4];
        int row = id - 4096;
        int t = tid;
        float v[4];
        if (f) {
            float4 f4 = ((const float4*)x)[(size_t)row * 256 + t];
            v[0] = f4.x; v[1] = f4.y; v[2] = f4.z; v[3] = f4.w;
        } else {
            ushort4 uv = ((const ushort4*)x)[(size_t)row * 256 + t];
            v[0] = bf2f(uv.x); v[1] = bf2f(uv.y); v[2] = bf2f(uv.z); v[3] = bf2f(uv.w);
        }
        float s = v[0] + v[1] + v[2] + v[3];
        float q = v[0]*v[0] + v[1]*v[1] + v[2]*v[2] + v[3]*v[3];
        for (int o = 1; o < 64; o <<= 1) { s += __shfl_xor(s, o); q += __shfl_xor(q, o); }
        int wv_ = t >> 6, ln = t & 63;
        if (ln == 0) { rs[wv_] = s; rq[wv_] = q; }
        __syncthreads();
        s = rs[0] + rs[1] + rs[2] + rs[3];
        q = rq[0] + rq[1] + rq[2] + rq[3];
        float mu   = s * (1.0f / D_);
        float var  = q * (1.0f / D_) - mu * mu;
        float rstd = rsqrtf(var + 1e-5f);
        u16 o4[4];
        for (int i = 0; i < 4; i++) {
            float gv, bv_;
            if (f) { gv = ((const float*)lng)[t*4 + i]; bv_ = ((const float*)lnb)[t*4 + i]; }
            else   { gv = bf2f(((const u16*)lng)[t*4 + i]); bv_ = bf2f(((const u16*)lnb)[t*4 + i]); }
            o4[i] = f2bf((v[i] - mu) * rstd * gv + bv_);
        }
        ushort4 ov; ov.x = o4[0]; ov.y = o4[1]; ov.z = o4[2]; ov.w = o4[3];
        *(ushort4*)(xn + (size_t)row * D_ + t * 4) = ov;
    } else {
        // ---- mask bias (+ vecs + flag on block 12288) ----
        __shared__ int sb[4];
        int k = id - 12288;                  // 0..7
        int bits = 0;
        for (int i = tid; i < B_ * T_; i += 256)
            if (m[i]) bits |= (i & 7);
        for (int o = 1; o < 64; o <<= 1) bits |= __shfl_xor(bits, o);
        if ((tid & 63) == 0) sb[tid >> 6] = bits;
        __syncthreads();
        bits = sb[0] | sb[1] | sb[2] | sb[3];
        int stride = (bits & 1) ? 1 : (bits & 2) ? 2 : (bits & 4) ? 4 : 8;
        for (int i = tid; i < 1024; i += 256) {
            int idx = k * 1024 + i;
            msk[idx] = m[(size_t)idx * stride] ? -200.f : 0.f;
        }
        if (k == 0) {
            if (tid == 0) *flag = f;
            const void* ss[6] = {bq, bk, bv, bo, lng, lnb};
            for (int t = 0; t < 6; t++) {
                const void* s = ss[t];
                for (int i = tid; i < 1024; i += 256)
                    vecs[t * 1024 + i] = f ? f2bf(((const float*)s)[i]) : ((const u16*)s)[i];
            }
        }
    }
}

// ------------- GEMM C = A[8192,1024] . W[1024,1024]^T + bias, *scale -------------
// R16: swap branch HOISTED out of the K-loop (R15: in-loop runtime branch
// fenced the scheduler -> +28us GEMM regression). Two branch-free K-loops;
// only the MFMA operand order differs. Swapped (Q/K/final): output C^T-mapped,
// lane holds 4 consecutive C-cols at a fixed row -> 16x vector stores +
// lane-local l2norm. V slice: original order + transposed store.
__global__ __launch_bounds__(256) void gemm_bt(
    const u16* __restrict__ A,
    const u16* __restrict__ W0, const u16* __restrict__ W1, const u16* __restrict__ W2,
    const u16* __restrict__ bias_all, int bias_idx0,
    u16* __restrict__ C0, u16* __restrict__ C1, u16* __restrict__ C2,
    float scale, const int* __restrict__ flag, int use_flag, int qkv_mode)
{
    const int K = 1024, N = 1024;
    const u16* W; const u16* bias; u16* C;
    if (blockIdx.z == 0)      { W = W0; bias = bias_all + (size_t)bias_idx0 * 1024;       C = C0; }
    else if (blockIdx.z == 1) { W = W1; bias = bias_all + (size_t)(bias_idx0 + 1) * 1024; C = C1; }
    else                      { W = W2; bias = bias_all + (size_t)(bias_idx0 + 2) * 1024; C = C2; }

    __shared__ u16 As[128 * 32];   // no pad: required by global_load_lds layout
    __shared__ u16 Bs[128 * 32];

    int tid  = threadIdx.x;
    int wave = tid >> 6, lane = tid & 63;
    int wm = wave >> 1, wn = wave & 1;
    int quad = lane >> 4, l16 = lane & 15;
    int bm = blockIdx.x * 128, bn = blockIdx.y * 128;   // x = row tile (XCD locality)

    int do_swap = !(qkv_mode && blockIdx.z == 2);       // all but V slice

    f32x4 acc[4][4];
    const f32x4 fz = {0.f, 0.f, 0.f, 0.f};
    for (int i = 0; i < 4; i++) for (int j = 0; j < 4; j++) acc[i][j] = fz;

    int srow = lane >> 2;
    int scol = (lane & 3) * 8;
    const u16* gA0 = A + (size_t)(bm + wave * 32 + srow) * K + scol;
    const u16* gB0 = W + (size_t)(bn + wave * 32 + srow) * K + scol;

#define GEMM_STAGE(K0) do {                                                     \
    for (int i = 0; i < 2; i++) {                                               \
        __builtin_amdgcn_global_load_lds(                                       \
            (const __attribute__((address_space(1))) void*)(gA0 + (size_t)i * 16 * K + (K0)), \
            (__attribute__((address_space(3))) void*)(As + (wave * 32 + i * 16) * 32), \
            16, 0, 0);                                                          \
        __builtin_amdgcn_global_load_lds(                                       \
            (const __attribute__((address_space(1))) void*)(gB0 + (size_t)i * 16 * K + (K0)), \
            (__attribute__((address_space(3))) void*)(Bs + (wave * 32 + i * 16) * 32), \
            16, 0, 0);                                                          \
    }                                                                           \
} while (0)
#define GEMM_LOAD_AB()                                                          \
    short8 a[4], b[4];                                                          \
    for (int i = 0; i < 4; i++)                                                 \
        a[i] = *(const short8*)(As + (wm * 64 + i * 16 + l16) * 32 + quad * 8); \
    for (int j = 0; j < 4; j++)                                                 \
        b[j] = *(const short8*)(Bs + (wn * 64 + j * 16 + l16) * 32 + quad * 8)

    if (do_swap) {
        for (int k0 = 0; k0 < K; k0 += 32) {
            GEMM_STAGE(k0);
            __syncthreads();
            GEMM_LOAD_AB();
            for (int i = 0; i < 4; i++)
                for (int j = 0; j < 4; j++)
                    acc[i][j] = __builtin_amdgcn_mfma_f32_16x16x32_bf16(b[j], a[i], acc[i][j], 0, 0, 0);
            __syncthreads();
        }
    } else {
        for (int k0 = 0; k0 < K; k0 += 32) {
            GEMM_STAGE(k0);
            __syncthreads();
            GEMM_LOAD_AB();
            for (int i = 0; i < 4; i++)
                for (int j = 0; j < 4; j++)
                    acc[i][j] = __builtin_amdgcn_mfma_f32_16x16x32_bf16(a[i], b[j], acc[i][j], 0, 0, 0);
            __syncthreads();
        }
    }
#undef GEMM_STAGE
#undef GEMM_LOAD_AB

    if (qkv_mode && blockIdx.z == 2) {
        // V (non-swapped): transposed store Vt[((b*16+h)*64+d)*2048 + t]
        for (int j = 0; j < 4; j++) {
            int col = bn + wn * 64 + j * 16 + l16;
            int h = col >> 6, d = col & 63;
            float bi = bf2f(bias[col]);
            for (int i = 0; i < 4; i++) {
                int row0 = bm + wm * 64 + i * 16 + quad * 4;
                int bq = row0 >> 11, t0 = row0 & 2047;
                ushort4 pk;
                pk.x = f2bf(acc[i][j][0] + bi); pk.y = f2bf(acc[i][j][1] + bi);
                pk.z = f2bf(acc[i][j][2] + bi); pk.w = f2bf(acc[i][j][3] + bi);
                *(ushort4*)(C + ((size_t)((bq * 16 + h) * 64 + d)) * 2048 + t0) = pk;
            }
        }
        return;
    }

    // swapped epilogues: lane holds cols bn+wn*64+j*16+quad*4 .. +3 at row
    // bm+wm*64+i*16+l16. Bias hoisted: 4 ushort4 loads.
    float bi[4][4];
    for (int j = 0; j < 4; j++) {
        ushort4 b4 = *(const ushort4*)(bias + bn + wn * 64 + j * 16 + quad * 4);
        bi[j][0] = bf2f(b4.x); bi[j][1] = bf2f(b4.y);
        bi[j][2] = bf2f(b4.z); bi[j][3] = bf2f(b4.w);
    }

    if (qkv_mode) {
        // Q/K: bias + per-head l2norm (+QSCALE for Q); head = the wave's 64 cols
        float sc2 = (blockIdx.z == 0) ? QSCALE_ : 1.0f;
        for (int i = 0; i < 4; i++) {
            int row = bm + wm * 64 + i * 16 + l16;
            float v[4][4]; float s = 0.f;
            for (int j = 0; j < 4; j++)
                for (int r = 0; r < 4; r++) {
                    float val = acc[i][j][r] + bi[j][r];
                    v[j][r] = val; s += val * val;
                }
            s += __shfl_xor(s, 16);
            s += __shfl_xor(s, 32);
            float scl = sc2 / fmaxf(sqrtf(s), 1e-8f);
            for (int j = 0; j < 4; j++) {
                ushort4 pk;
                pk.x = f2bf(v[j][0] * scl); pk.y = f2bf(v[j][1] * scl);
                pk.z = f2bf(v[j][2] * scl); pk.w = f2bf(v[j][3] * scl);
                *(ushort4*)(C + (size_t)row * N + bn + wn * 64 + j * 16 + quad * 4) = pk;
            }
        }
        return;
    }

    int f32out = use_flag ? *flag : 0;
    for (int i = 0; i < 4; i++) {
        int row = bm + wm * 64 + i * 16 + l16;
        for (int j = 0; j < 4; j++) {
            int colb = bn + wn * 64 + j * 16 + quad * 4;
            float o0 = (acc[i][j][0] + bi[j][0]) * scale;
            float o1 = (acc[i][j][1] + bi[j][1]) * scale;
            float o2 = (acc[i][j][2] + bi[j][2]) * scale;
            float o3 = (acc[i][j][3] + bi[j][3]) * scale;
            if (f32out) {
                float4 f4 = {o0, o1, o2, o3};
                *(float4*)(&((float*)C)[(size_t)row * N + colb]) = f4;
            } else {
                ushort4 pk;
                pk.x = f2bf(o0); pk.y = f2bf(o1); pk.z = f2bf(o2); pk.w = f2bf(o3);
                *(ushort4*)(C + (size_t)row * N + colb) = pk;
            }
        }
    }
}

// ---------------- Flash-style attention v12 (unchanged from R15) ----------------
// 117.2us measured; MfmaUtil 27.6. rowsum via all-ones MFMA confirmed.
__global__ __launch_bounds__(256, 4) void attn_kernel(
    const u16* __restrict__ Q, const u16* __restrict__ Kg,
    const u16* __restrict__ Vt, const float* __restrict__ msk,
    u16* __restrict__ Oout)
{
    __shared__ __align__(16) u16 Ks[2 * 64 * 64];   // [buf][rho(key)][dk], chunk-swizzled
    __shared__ __align__(16) u16 VTs[2 * 64 * 64];  // [buf][dk][key],      chunk-swizzled

    int tid  = threadIdx.x;
    int wave = tid >> 6, lane = tid & 63;
    int quad = lane >> 4, l16 = lane & 15;
    int q0 = blockIdx.y * 128;                    // XCD locality: x = bh
    int b  = blockIdx.x >> 4, h = blockIdx.x & 15;
    const size_t base  = (size_t)b * T_ * D_ + h * DK_;
    const size_t vbase = (size_t)((b * 16 + h) * 64) * T_;

    // Q fragments for two 16-query groups (pre-normalized, pre-scaled)
    short8 qa[2][2];
    for (int g = 0; g < 2; g++) {
        const u16* qrow = Q + base + (size_t)(q0 + wave * 32 + g * 16 + l16) * D_;
        qa[g][0] = *(const short8*)(qrow + quad * 8);
        qa[g][1] = *(const short8*)(qrow + 32 + quad * 8);
    }

    const float* mq = msk + b * T_ + quad * 8;   // + kt + j2*32 + s*4

    // gload_lds staging geometry: lane l -> (row rL = w*8+p*32+(l>>3), chunk l&7)
    int rL0 = wave * 8 + (lane >> 3);
    int rL1 = rL0 + 32;
    int c   = lane & 7;
    int k0i = (rL0 & 32) + ((rL0 >> 2) & 3) * 8 + ((rL0 >> 4) & 1) * 4 + (rL0 & 3);
    int k1i = (rL1 & 32) + ((rL1 >> 2) & 3) * 8 + ((rL1 >> 4) & 1) * 4 + (rL1 & 3);
    const u16* kgs0 = Kg + base + (size_t)k0i * D_ + (c ^ (rL0 & 7)) * 8;
    const u16* kgs1 = Kg + base + (size_t)k1i * D_ + (c ^ (rL1 & 7)) * 8;
    const u16* vgs0 = Vt + vbase + (size_t)rL0 * T_ + (c ^ (rL0 & 7)) * 8;
    const u16* vgs1 = Vt + vbase + (size_t)rL1 * T_ + (c ^ (rL1 & 7)) * 8;
    u16* kd0 = Ks  + (wave * 8) * 64;            // wave-uniform LDS bases
    u16* kd1 = Ks  + (wave * 8 + 32) * 64;
    u16* vd0 = VTs + (wave * 8) * 64;
    u16* vd1 = VTs + (wave * 8 + 32) * 64;

#define STAGE(BUF, KOFF) do {                                                   \
    __builtin_amdgcn_global_load_lds(                                           \
        (const __attribute__((address_space(1))) void*)(kgs0 + (size_t)(KOFF) * D_), \
        (__attribute__((address_space(3))) void*)(kd0 + (BUF) * 4096), 16, 0, 0); \
    __builtin_amdgcn_global_load_lds(                                           \
        (const __attribute__((address_space(1))) void*)(kgs1 + (size_t)(KOFF) * D_), \
        (__attribute__((address_space(3))) void*)(kd1 + (BUF) * 4096), 16, 0, 0); \
    __builtin_amdgcn_global_load_lds(                                           \
        (const __attribute__((address_space(1))) void*)(vgs0 + (KOFF)),         \
        (__attribute__((address_space(3))) void*)(vd0 + (BUF) * 4096), 16, 0, 0); \
    __builtin_amdgcn_global_load_lds(                                           \
        (const __attribute__((address_space(1))) void*)(vgs1 + (KOFF)),         \
        (__attribute__((address_space(3))) void*)(vd1 + (BUF) * 4096), 16, 0, 0); \
} while (0)

    // prologue: stage tile 0 into buffer 0
    STAGE(0, 0);
    __syncthreads();

    // per-lane LDS read bases (buffer + subtile offsets fold to immediates)
    const u16* kr_lo = Ks + l16 * 64 + ((quad ^ (l16 & 7)) * 8);        // dk 0..31
    const u16* kr_hi = Ks + l16 * 64 + (((4 + quad) ^ (l16 & 7)) * 8);  // dk 32..63
    const u16* vr0 = VTs + l16 * 64 + ((quad ^ (l16 & 7)) * 8);         // j2=0
    const u16* vr1 = VTs + l16 * 64 + (((4 + quad) ^ (l16 & 7)) * 8);   // j2=1

    f32x4 o_acc[2][4];   // O^T: lane holds d = jd*16+quad*4+r, q = l16
    for (int g = 0; g < 2; g++) for (int j = 0; j < 4; j++) o_acc[g][j] = f32x4{0.f, 0.f, 0.f, 0.f};
    f32x4 rs_acc[2] = {f32x4{0.f,0.f,0.f,0.f}, f32x4{0.f,0.f,0.f,0.f}};
    const short8 vone = {(short)0x3F80, (short)0x3F80, (short)0x3F80, (short)0x3F80,
                         (short)0x3F80, (short)0x3F80, (short)0x3F80, (short)0x3F80};

#define TILE_BODY(CUR, NXT, KT) do {                                            \
    int ktn = ((KT) + 64) & (T_ - 1);                                           \
    STAGE(NXT, ktn);                                                            \
    f32x4 pmt[2][2];                                                            \
    for (int j2 = 0; j2 < 2; j2++)                                              \
        for (int s = 0; s < 2; s++)                                             \
            pmt[j2][s] = *(const f32x4*)(mq + (KT) + j2 * 32 + s * 4);          \
    __builtin_amdgcn_s_setprio(1);                                              \
    for (int j2 = 0; j2 < 2; j2++) {                                            \
        unsigned pw[2][4];                                                      \
        for (int s = 0; s < 2; s++) {                                           \
            short8 kb0 = *(const short8*)(kr_lo + (CUR) * 4096 + (j2 * 32 + s * 16) * 64); \
            short8 kb1 = *(const short8*)(kr_hi + (CUR) * 4096 + (j2 * 32 + s * 16) * 64); \
            for (int g = 0; g < 2; g++) {                                       \
                f32x4 s4 = __builtin_amdgcn_mfma_f32_16x16x32_bf16(kb0, qa[g][0], pmt[j2][s], 0, 0, 0); \
                s4       = __builtin_amdgcn_mfma_f32_16x16x32_bf16(kb1, qa[g][1], s4, 0, 0, 0); \
                float p0 = __builtin_exp2f(s4[0]);                              \
                float p1 = __builtin_exp2f(s4[1]);                              \
                float p2 = __builtin_exp2f(s4[2]);                              \
                float p3 = __builtin_exp2f(s4[3]);                              \
                pw[g][s * 2]     = pack_bf16_hu(p0, p1);                        \
                pw[g][s * 2 + 1] = pack_bf16_hu(p2, p3);                        \
            }                                                                   \
        }                                                                       \
        short8 pb[2];                                                           \
        __builtin_memcpy(&pb[0], &pw[0][0], 16);                                \
        __builtin_memcpy(&pb[1], &pw[1][0], 16);                                \
        rs_acc[0] = __builtin_amdgcn_mfma_f32_16x16x32_bf16(vone, pb[0], rs_acc[0], 0, 0, 0); \
        rs_acc[1] = __builtin_amdgcn_mfma_f32_16x16x32_bf16(vone, pb[1], rs_acc[1], 0, 0, 0); \
        const u16* vr = (j2 ? vr1 : vr0) + (CUR) * 4096;                        \
        for (int jd = 0; jd < 4; jd++) {                                        \
            short8 vv = *(const short8*)(vr + jd * 16 * 64);                    \
            o_acc[0][jd] = __builtin_amdgcn_mfma_f32_16x16x32_bf16(vv, pb[0], o_acc[0][jd], 0, 0, 0); \
            o_acc[1][jd] = __builtin_amdgcn_mfma_f32_16x16x32_bf16(vv, pb[1], o_acc[1][jd], 0, 0, 0); \
        }                                                                       \
    }                                                                           \
    __builtin_amdgcn_s_setprio(0);                                              \
    __syncthreads();                                                            \
} while (0)

    for (int kt = 0; kt < T_; kt += 128) {
        TILE_BODY(0, 1, kt);
        TILE_BODY(1, 0, kt + 64);
    }
#undef TILE_BODY
#undef STAGE

    // epilogue: rs_acc holds the full row-sum replicated (no shfl needed)
    for (int g = 0; g < 2; g++) {
        float inv = 1.0f / fmaxf(rs_acc[g][0], 1e-20f);
        size_t orow = base + (size_t)(q0 + wave * 32 + g * 16 + l16) * D_;
        for (int jd = 0; jd < 4; jd++) {
            ushort4 pk;
            pk.x = f2bf(o_acc[g][jd][0] * inv);
            pk.y = f2bf(o_acc[g][jd][1] * inv);
            pk.z = f2bf(o_acc[g][jd][2] * inv);
            pk.w = f2bf(o_acc[g][jd][3] * inv);
            *(ushort4*)(Oout + orow + jd * 16 + quad * 4) = pk;
        }
    }
}

extern "C" void kernel_launch(void* const* d_in, const int* in_sizes, int n_in,
                              void* d_out, int out_size, void* d_ws, size_t ws_size,
                              hipStream_t stream)
{
    const void* x    = d_in[0];
    const u8*   mask = (const u8*)d_in[1];
    const void* wq   = d_in[2];
    const void* bq   = d_in[3];
    const void* wk   = d_in[4];
    const void* bk   = d_in[5];
    const void* wv   = d_in[6];
    const void* bv   = d_in[7];
    const void* wo   = d_in[8];
    const void* bo   = d_in[9];
    const void* lng  = d_in[10];
    const void* lnb  = d_in[11];

    const size_t NTOK = (size_t)B_ * T_;          // 8192
    u16* xn  = (u16*)d_ws;                        // 16.8 MB; reused as attention output
    u16* Kb  = xn + NTOK * D_;                    // 16.8 MB
    u16* Vtb = Kb + NTOK * D_;                    // 16.8 MB (transposed layout)
    u16* wqc = Vtb + NTOK * D_;                   // 2 MB each
    u16* wkc = wqc + (size_t)D_ * D_;
    u16* wvc = wkc + (size_t)D_ * D_;
    u16* woc = wvc + (size_t)D_ * D_;
    u16* vecs = woc + (size_t)D_ * D_;            // 6 x 1024: bq,bk,bv,bo,ln_g,ln_b
    float* msk = (float*)(vecs + 6 * 1024);       // 32 KB float mask bias (0 / -200)
    int* flag = (int*)(msk + 8192);               // dtype flag: 1 = fp32 inputs
    u16* Qb  = (u16*)d_out;                       // Q in d_out (dead until final GEMM)

    mega_prep<<<dim3(12296), 256, 0, stream>>>(
        (const u16*)x, mask, wq, wk, wv, wo, bq, bk, bv, bo, lng, lnb,
        wqc, wkc, wvc, woc, vecs, msk, flag, xn);
    gemm_bt<<<dim3(64, 8, 3), 256, 0, stream>>>(xn, wqc, wkc, wvc, vecs, 0, Qb, Kb, Vtb, 1.0f, flag, 0, 1);
    attn_kernel<<<dim3(64, 16), 256, 0, stream>>>(Qb, Kb, Vtb, msk, xn);
    gemm_bt<<<dim3(64, 8, 1), 256, 0, stream>>>(xn, woc, woc, woc, vecs, 3, (u16*)d_out, (u16*)d_out, (u16*)d_out, 0.5f, flag, 1, 0);
}

// Round 18
// 330.676 us; speedup vs baseline: 1.1073x; 1.0307x over previous
//
#include <hip/hip_runtime.h>
#include <hip/hip_bf16.h>
#include <cstdint>
#include <cstddef>
#include <cstring>

typedef unsigned short u16;
typedef unsigned char u8;
typedef __attribute__((ext_vector_type(8))) short short8;   // 8 x bf16 (4 VGPRs)
typedef __attribute__((ext_vector_type(4))) float f32x4;    // MFMA C/D

#define B_    4
#define T_    2048
#define D_    1024
#define H_    16
#define DK_   64
// SCALE * log2(e): scores exponentiate via 2^x (single v_exp_f32)
#define QSCALE_ 0.18033688011112042f

__device__ __forceinline__ float bf2f(u16 u) {
    unsigned int x = ((unsigned int)u) << 16;
    float f; __builtin_memcpy(&f, &x, 4); return f;
}
__device__ __forceinline__ u16 f2bf(float f) {
    unsigned int x; __builtin_memcpy(&x, &f, 4);
    x += 0x7fffu + ((x >> 16) & 1u);   // round-to-nearest-even
    return (u16)(x >> 16);
}
// pack two floats to bf16x2 (round-half-up): 2 adds + 1 v_perm_b32.
__device__ __forceinline__ unsigned pack_bf16_hu(float lo, float hi) {
    unsigned a, b;
    __builtin_memcpy(&a, &lo, 4);
    __builtin_memcpy(&b, &hi, 4);
    return __builtin_amdgcn_perm(b + 0x8000u, a + 0x8000u, 0x07060302u);
}

// ---------------- Fused prep+convert+LN mega-kernel ----------------
__device__ __forceinline__ int sniff_flag(const u16* __restrict__ x, int tid) {
    __shared__ int sc[4];
    int cnt = 0;
    for (int i = tid; i < 512; i += 256) {
        int e = (x[8 * i] >> 7) & 0xFF;     // low u16 of f32 / real bf16
        if (e > 137 || (e >= 1 && e < 97)) cnt++;
    }
    for (int o = 1; o < 64; o <<= 1) cnt += __shfl_xor(cnt, o);
    if ((tid & 63) == 0) sc[tid >> 6] = cnt;
    __syncthreads();
    return (sc[0] + sc[1] + sc[2] + sc[3] > 128) ? 1 : 0;   // fp32 ~83% hit rate
}

__global__ __launch_bounds__(256) void mega_prep(
    const u16* __restrict__ x, const u8* __restrict__ m,
    const void* wq, const void* wk, const void* wv, const void* wo,
    const void* bq, const void* bk, const void* bv, const void* bo,
    const void* lng, const void* lnb,
    u16* __restrict__ wqc, u16* __restrict__ wkc,
    u16* __restrict__ wvc, u16* __restrict__ woc,
    u16* __restrict__ vecs, float* __restrict__ msk, int* flag,
    u16* __restrict__ xn)
{
    int tid = threadIdx.x;
    int f = sniff_flag(x, tid);
    int id = blockIdx.x;

    if (id < 4096) {
        // ---- weight canonicalize: 4 x [1024,1024] -> bf16 ----
        int mat = id >> 10;
        const void* s = (mat == 0) ? wq : (mat == 1) ? wk : (mat == 2) ? wv : wo;
        u16* d = (mat == 0) ? wqc : (mat == 1) ? wkc : (mat == 2) ? wvc : woc;
        int i4 = (id & 1023) * 256 + tid;
        if (f) {
            float4 v = ((const float4*)s)[i4];
            ushort4 o; o.x = f2bf(v.x); o.y = f2bf(v.y); o.z = f2bf(v.z); o.w = f2bf(v.w);
            ((ushort4*)d)[i4] = o;
        } else {
            ((ushort4*)d)[i4] = ((const ushort4*)s)[i4];
        }
    } else if (id < 12288) {
        // ---- LayerNorm row ----
        __shared__ float rs[4], rq[4];
        int row = id - 4096;
        int t = tid;
        float v[4];
        if (f) {
            float4 f4 = ((const float4*)x)[(size_t)row * 256 + t];
            v[0] = f4.x; v[1] = f4.y; v[2] = f4.z; v[3] = f4.w;
        } else {
            ushort4 uv = ((const ushort4*)x)[(size_t)row * 256 + t];
            v[0] = bf2f(uv.x); v[1] = bf2f(uv.y); v[2] = bf2f(uv.z); v[3] = bf2f(uv.w);
        }
        float s = v[0] + v[1] + v[2] + v[3];
        float q = v[0]*v[0] + v[1]*v[1] + v[2]*v[2] + v[3]*v[3];
        for (int o = 1; o < 64; o <<= 1) { s += __shfl_xor(s, o); q += __shfl_xor(q, o); }
        int wv_ = t >> 6, ln = t & 63;
        if (ln == 0) { rs[wv_] = s; rq[wv_] = q; }
        __syncthreads();
        s = rs[0] + rs[1] + rs[2] + rs[3];
        q = rq[0] + rq[1] + rq[2] + rq[3];
        float mu   = s * (1.0f / D_);
        float var  = q * (1.0f / D_) - mu * mu;
        float rstd = rsqrtf(var + 1e-5f);
        u16 o4[4];
        for (int i = 0; i < 4; i++) {
            float gv, bv_;
            if (f) { gv = ((const float*)lng)[t*4 + i]; bv_ = ((const float*)lnb)[t*4 + i]; }
            else   { gv = bf2f(((const u16*)lng)[t*4 + i]); bv_ = bf2f(((const u16*)lnb)[t*4 + i]); }
            o4[i] = f2bf((v[i] - mu) * rstd * gv + bv_);
        }
        ushort4 ov; ov.x = o4[0]; ov.y = o4[1]; ov.z = o4[2]; ov.w = o4[3];
        *(ushort4*)(xn + (size_t)row * D_ + t * 4) = ov;
    } else {
        // ---- mask bias (+ vecs + flag on block 12288) ----
        __shared__ int sb[4];
        int k = id - 12288;                  // 0..7
        int bits = 0;
        for (int i = tid; i < B_ * T_; i += 256)
            if (m[i]) bits |= (i & 7);
        for (int o = 1; o < 64; o <<= 1) bits |= __shfl_xor(bits, o);
        if ((tid & 63) == 0) sb[tid >> 6] = bits;
        __syncthreads();
        bits = sb[0] | sb[1] | sb[2] | sb[3];
        int stride = (bits & 1) ? 1 : (bits & 2) ? 2 : (bits & 4) ? 4 : 8;
        for (int i = tid; i < 1024; i += 256) {
            int idx = k * 1024 + i;
            msk[idx] = m[(size_t)idx * stride] ? -200.f : 0.f;
        }
        if (k == 0) {
            if (tid == 0) *flag = f;
            const void* ss[6] = {bq, bk, bv, bo, lng, lnb};
            for (int t = 0; t < 6; t++) {
                const void* s = ss[t];
                for (int i = tid; i < 1024; i += 256)
                    vecs[t * 1024 + i] = f ? f2bf(((const float*)s)[i]) : ((const u16*)s)[i];
            }
        }
    }
}

// ------------- GEMM C = A[8192,1024] . W[1024,1024]^T + bias, *scale -------------
// R18: BK=64 via dual BK=32 sub-buffers. Stage BOTH sub-tiles, ONE barrier,
// 32 MFMAs, ONE barrier -> barrier+vmcnt-drain count halves (64 -> 32 per
// block); per-sub-tile LDS addressing identical to the proven [128][32]
// layout (no new swizzle risk). "rest" has been pinned at ~222us across all
// GEMM tweaks (XCD swizzle, epilogue vec) -> K-loop barrier structure is the
// binding constraint (m97-drain). Swap branch hoisted (R16). LDS 32KB.
__global__ __launch_bounds__(256) void gemm_bt(
    const u16* __restrict__ A,
    const u16* __restrict__ W0, const u16* __restrict__ W1, const u16* __restrict__ W2,
    const u16* __restrict__ bias_all, int bias_idx0,
    u16* __restrict__ C0, u16* __restrict__ C1, u16* __restrict__ C2,
    float scale, const int* __restrict__ flag, int use_flag, int qkv_mode)
{
    const int K = 1024, N = 1024;
    const u16* W; const u16* bias; u16* C;
    if (blockIdx.z == 0)      { W = W0; bias = bias_all + (size_t)bias_idx0 * 1024;       C = C0; }
    else if (blockIdx.z == 1) { W = W1; bias = bias_all + (size_t)(bias_idx0 + 1) * 1024; C = C1; }
    else                      { W = W2; bias = bias_all + (size_t)(bias_idx0 + 2) * 1024; C = C2; }

    __shared__ u16 As[2][128 * 32];   // [sub][row][32]; layout per sub = proven
    __shared__ u16 Bs[2][128 * 32];

    int tid  = threadIdx.x;
    int wave = tid >> 6, lane = tid & 63;
    int wm = wave >> 1, wn = wave & 1;
    int quad = lane >> 4, l16 = lane & 15;
    int bm = blockIdx.x * 128, bn = blockIdx.y * 128;   // x = row tile (XCD locality)

    int do_swap = !(qkv_mode && blockIdx.z == 2);       // all but V slice

    f32x4 acc[4][4];
    const f32x4 fz = {0.f, 0.f, 0.f, 0.f};
    for (int i = 0; i < 4; i++) for (int j = 0; j < 4; j++) acc[i][j] = fz;

    int srow = lane >> 2;
    int scol = (lane & 3) * 8;
    const u16* gA0 = A + (size_t)(bm + wave * 32 + srow) * K + scol;
    const u16* gB0 = W + (size_t)(bn + wave * 32 + srow) * K + scol;

#define GEMM_STAGE(K0) do {                                                     \
    for (int s = 0; s < 2; s++)                                                 \
        for (int i = 0; i < 2; i++) {                                           \
            __builtin_amdgcn_global_load_lds(                                   \
                (const __attribute__((address_space(1))) void*)(gA0 + (size_t)i * 16 * K + (K0) + s * 32), \
                (__attribute__((address_space(3))) void*)(As[s] + (wave * 32 + i * 16) * 32), \
                16, 0, 0);                                                      \
            __builtin_amdgcn_global_load_lds(                                   \
                (const __attribute__((address_space(1))) void*)(gB0 + (size_t)i * 16 * K + (K0) + s * 32), \
                (__attribute__((address_space(3))) void*)(Bs[s] + (wave * 32 + i * 16) * 32), \
                16, 0, 0);                                                      \
        }                                                                       \
} while (0)

    if (do_swap) {
        for (int k0 = 0; k0 < K; k0 += 64) {
            GEMM_STAGE(k0);
            __syncthreads();
            for (int s = 0; s < 2; s++) {
                short8 a[4], b[4];
                for (int i = 0; i < 4; i++)
                    a[i] = *(const short8*)(As[s] + (wm * 64 + i * 16 + l16) * 32 + quad * 8);
                for (int j = 0; j < 4; j++)
                    b[j] = *(const short8*)(Bs[s] + (wn * 64 + j * 16 + l16) * 32 + quad * 8);
                for (int i = 0; i < 4; i++)
                    for (int j = 0; j < 4; j++)
                        acc[i][j] = __builtin_amdgcn_mfma_f32_16x16x32_bf16(b[j], a[i], acc[i][j], 0, 0, 0);
            }
            __syncthreads();
        }
    } else {
        for (int k0 = 0; k0 < K; k0 += 64) {
            GEMM_STAGE(k0);
            __syncthreads();
            for (int s = 0; s < 2; s++) {
                short8 a[4], b[4];
                for (int i = 0; i < 4; i++)
                    a[i] = *(const short8*)(As[s] + (wm * 64 + i * 16 + l16) * 32 + quad * 8);
                for (int j = 0; j < 4; j++)
                    b[j] = *(const short8*)(Bs[s] + (wn * 64 + j * 16 + l16) * 32 + quad * 8);
                for (int i = 0; i < 4; i++)
                    for (int j = 0; j < 4; j++)
                        acc[i][j] = __builtin_amdgcn_mfma_f32_16x16x32_bf16(a[i], b[j], acc[i][j], 0, 0, 0);
            }
            __syncthreads();
        }
    }
#undef GEMM_STAGE

    if (qkv_mode && blockIdx.z == 2) {
        // V (non-swapped): transposed store Vt[((b*16+h)*64+d)*2048 + t]
        for (int j = 0; j < 4; j++) {
            int col = bn + wn * 64 + j * 16 + l16;
            int h = col >> 6, d = col & 63;
            float bi = bf2f(bias[col]);
            for (int i = 0; i < 4; i++) {
                int row0 = bm + wm * 64 + i * 16 + quad * 4;
                int bq = row0 >> 11, t0 = row0 & 2047;
                ushort4 pk;
                pk.x = f2bf(acc[i][j][0] + bi); pk.y = f2bf(acc[i][j][1] + bi);
                pk.z = f2bf(acc[i][j][2] + bi); pk.w = f2bf(acc[i][j][3] + bi);
                *(ushort4*)(C + ((size_t)((bq * 16 + h) * 64 + d)) * 2048 + t0) = pk;
            }
        }
        return;
    }

    // swapped epilogues: lane holds cols bn+wn*64+j*16+quad*4 .. +3 at row
    // bm+wm*64+i*16+l16. Bias hoisted: 4 ushort4 loads.
    float bi[4][4];
    for (int j = 0; j < 4; j++) {
        ushort4 b4 = *(const ushort4*)(bias + bn + wn * 64 + j * 16 + quad * 4);
        bi[j][0] = bf2f(b4.x); bi[j][1] = bf2f(b4.y);
        bi[j][2] = bf2f(b4.z); bi[j][3] = bf2f(b4.w);
    }

    if (qkv_mode) {
        // Q/K: bias + per-head l2norm (+QSCALE for Q); head = the wave's 64 cols
        float sc2 = (blockIdx.z == 0) ? QSCALE_ : 1.0f;
        for (int i = 0; i < 4; i++) {
            int row = bm + wm * 64 + i * 16 + l16;
            float v[4][4]; float s = 0.f;
            for (int j = 0; j < 4; j++)
                for (int r = 0; r < 4; r++) {
                    float val = acc[i][j][r] + bi[j][r];
                    v[j][r] = val; s += val * val;
                }
            s += __shfl_xor(s, 16);
            s += __shfl_xor(s, 32);
            float scl = sc2 / fmaxf(sqrtf(s), 1e-8f);
            for (int j = 0; j < 4; j++) {
                ushort4 pk;
                pk.x = f2bf(v[j][0] * scl); pk.y = f2bf(v[j][1] * scl);
                pk.z = f2bf(v[j][2] * scl); pk.w = f2bf(v[j][3] * scl);
                *(ushort4*)(C + (size_t)row * N + bn + wn * 64 + j * 16 + quad * 4) = pk;
            }
        }
        return;
    }

    int f32out = use_flag ? *flag : 0;
    for (int i = 0; i < 4; i++) {
        int row = bm + wm * 64 + i * 16 + l16;
        for (int j = 0; j < 4; j++) {
            int colb = bn + wn * 64 + j * 16 + quad * 4;
            float o0 = (acc[i][j][0] + bi[j][0]) * scale;
            float o1 = (acc[i][j][1] + bi[j][1]) * scale;
            float o2 = (acc[i][j][2] + bi[j][2]) * scale;
            float o3 = (acc[i][j][3] + bi[j][3]) * scale;
            if (f32out) {
                float4 f4 = {o0, o1, o2, o3};
                *(float4*)(&((float*)C)[(size_t)row * N + colb]) = f4;
            } else {
                ushort4 pk;
                pk.x = f2bf(o0); pk.y = f2bf(o1); pk.z = f2bf(o2); pk.w = f2bf(o3);
                *(ushort4*)(C + (size_t)row * N + colb) = pk;
            }
        }
    }
}

// ---------------- Flash-style attention v12 (unchanged; 117.2us measured) ----------------
__global__ __launch_bounds__(256, 4) void attn_kernel(
    const u16* __restrict__ Q, const u16* __restrict__ Kg,
    const u16* __restrict__ Vt, const float* __restrict__ msk,
    u16* __restrict__ Oout)
{
    __shared__ __align__(16) u16 Ks[2 * 64 * 64];   // [buf][rho(key)][dk], chunk-swizzled
    __shared__ __align__(16) u16 VTs[2 * 64 * 64];  // [buf][dk][key],      chunk-swizzled

    int tid  = threadIdx.x;
    int wave = tid >> 6, lane = tid & 63;
    int quad = lane >> 4, l16 = lane & 15;
    int q0 = blockIdx.y * 128;                    // XCD locality: x = bh
    int b  = blockIdx.x >> 4, h = blockIdx.x & 15;
    const size_t base  = (size_t)b * T_ * D_ + h * DK_;
    const size_t vbase = (size_t)((b * 16 + h) * 64) * T_;

    // Q fragments for two 16-query groups (pre-normalized, pre-scaled)
    short8 qa[2][2];
    for (int g = 0; g < 2; g++) {
        const u16* qrow = Q + base + (size_t)(q0 + wave * 32 + g * 16 + l16) * D_;
        qa[g][0] = *(const short8*)(qrow + quad * 8);
        qa[g][1] = *(const short8*)(qrow + 32 + quad * 8);
    }

    const float* mq = msk + b * T_ + quad * 8;   // + kt + j2*32 + s*4

    // gload_lds staging geometry: lane l -> (row rL = w*8+p*32+(l>>3), chunk l&7)
    int rL0 = wave * 8 + (lane >> 3);
    int rL1 = rL0 + 32;
    int c   = lane & 7;
    int k0i = (rL0 & 32) + ((rL0 >> 2) & 3) * 8 + ((rL0 >> 4) & 1) * 4 + (rL0 & 3);
    int k1i = (rL1 & 32) + ((rL1 >> 2) & 3) * 8 + ((rL1 >> 4) & 1) * 4 + (rL1 & 3);
    const u16* kgs0 = Kg + base + (size_t)k0i * D_ + (c ^ (rL0 & 7)) * 8;
    const u16* kgs1 = Kg + base + (size_t)k1i * D_ + (c ^ (rL1 & 7)) * 8;
    const u16* vgs0 = Vt + vbase + (size_t)rL0 * T_ + (c ^ (rL0 & 7)) * 8;
    const u16* vgs1 = Vt + vbase + (size_t)rL1 * T_ + (c ^ (rL1 & 7)) * 8;
    u16* kd0 = Ks  + (wave * 8) * 64;            // wave-uniform LDS bases
    u16* kd1 = Ks  + (wave * 8 + 32) * 64;
    u16* vd0 = VTs + (wave * 8) * 64;
    u16* vd1 = VTs + (wave * 8 + 32) * 64;

#define STAGE(BUF, KOFF) do {                                                   \
    __builtin_amdgcn_global_load_lds(                                           \
        (const __attribute__((address_space(1))) void*)(kgs0 + (size_t)(KOFF) * D_), \
        (__attribute__((address_space(3))) void*)(kd0 + (BUF) * 4096), 16, 0, 0); \
    __builtin_amdgcn_global_load_lds(                                           \
        (const __attribute__((address_space(1))) void*)(kgs1 + (size_t)(KOFF) * D_), \
        (__attribute__((address_space(3))) void*)(kd1 + (BUF) * 4096), 16, 0, 0); \
    __builtin_amdgcn_global_load_lds(                                           \
        (const __attribute__((address_space(1))) void*)(vgs0 + (KOFF)),         \
        (__attribute__((address_space(3))) void*)(vd0 + (BUF) * 4096), 16, 0, 0); \
    __builtin_amdgcn_global_load_lds(                                           \
        (const __attribute__((address_space(1))) void*)(vgs1 + (KOFF)),         \
        (__attribute__((address_space(3))) void*)(vd1 + (BUF) * 4096), 16, 0, 0); \
} while (0)

    // prologue: stage tile 0 into buffer 0
    STAGE(0, 0);
    __syncthreads();

    // per-lane LDS read bases (buffer + subtile offsets fold to immediates)
    const u16* kr_lo = Ks + l16 * 64 + ((quad ^ (l16 & 7)) * 8);        // dk 0..31
    const u16* kr_hi = Ks + l16 * 64 + (((4 + quad) ^ (l16 & 7)) * 8);  // dk 32..63
    const u16* vr0 = VTs + l16 * 64 + ((quad ^ (l16 & 7)) * 8);         // j2=0
    const u16* vr1 = VTs + l16 * 64 + (((4 + quad) ^ (l16 & 7)) * 8);   // j2=1

    f32x4 o_acc[2][4];   // O^T: lane holds d = jd*16+quad*4+r, q = l16
    for (int g = 0; g < 2; g++) for (int j = 0; j < 4; j++) o_acc[g][j] = f32x4{0.f, 0.f, 0.f, 0.f};
    f32x4 rs_acc[2] = {f32x4{0.f,0.f,0.f,0.f}, f32x4{0.f,0.f,0.f,0.f}};
    const short8 vone = {(short)0x3F80, (short)0x3F80, (short)0x3F80, (short)0x3F80,
                         (short)0x3F80, (short)0x3F80, (short)0x3F80, (short)0x3F80};

#define TILE_BODY(CUR, NXT, KT) do {                                            \
    int ktn = ((KT) + 64) & (T_ - 1);                                           \
    STAGE(NXT, ktn);                                                            \
    f32x4 pmt[2][2];                                                            \
    for (int j2 = 0; j2 < 2; j2++)                                              \
        for (int s = 0; s < 2; s++)                                             \
            pmt[j2][s] = *(const f32x4*)(mq + (KT) + j2 * 32 + s * 4);          \
    __builtin_amdgcn_s_setprio(1);                                              \
    for (int j2 = 0; j2 < 2; j2++) {                                            \
        unsigned pw[2][4];                                                      \
        for (int s = 0; s < 2; s++) {                                           \
            short8 kb0 = *(const short8*)(kr_lo + (CUR) * 4096 + (j2 * 32 + s * 16) * 64); \
            short8 kb1 = *(const short8*)(kr_hi + (CUR) * 4096 + (j2 * 32 + s * 16) * 64); \
            for (int g = 0; g < 2; g++) {                                       \
                f32x4 s4 = __builtin_amdgcn_mfma_f32_16x16x32_bf16(kb0, qa[g][0], pmt[j2][s], 0, 0, 0); \
                s4       = __builtin_amdgcn_mfma_f32_16x16x32_bf16(kb1, qa[g][1], s4, 0, 0, 0); \
                float p0 = __builtin_exp2f(s4[0]);                              \
                float p1 = __builtin_exp2f(s4[1]);                              \
                float p2 = __builtin_exp2f(s4[2]);                              \
                float p3 = __builtin_exp2f(s4[3]);                              \
                pw[g][s * 2]     = pack_bf16_hu(p0, p1);                        \
                pw[g][s * 2 + 1] = pack_bf16_hu(p2, p3);                        \
            }                                                                   \
        }                                                                       \
        short8 pb[2];                                                           \
        __builtin_memcpy(&pb[0], &pw[0][0], 16);                                \
        __builtin_memcpy(&pb[1], &pw[1][0], 16);                                \
        rs_acc[0] = __builtin_amdgcn_mfma_f32_16x16x32_bf16(vone, pb[0], rs_acc[0], 0, 0, 0); \
        rs_acc[1] = __builtin_amdgcn_mfma_f32_16x16x32_bf16(vone, pb[1], rs_acc[1], 0, 0, 0); \
        const u16* vr = (j2 ? vr1 : vr0) + (CUR) * 4096;                        \
        for (int jd = 0; jd < 4; jd++) {                                        \
            short8 vv = *(const short8*)(vr + jd * 16 * 64);                    \
            o_acc[0][jd] = __builtin_amdgcn_mfma_f32_16x16x32_bf16(vv, pb[0], o_acc[0][jd], 0, 0, 0); \
            o_acc[1][jd] = __builtin_amdgcn_mfma_f32_16x16x32_bf16(vv, pb[1], o_acc[1][jd], 0, 0, 0); \
        }                                                                       \
    }                                                                           \
    __builtin_amdgcn_s_setprio(0);                                              \
    __syncthreads();                                                            \
} while (0)

    for (int kt = 0; kt < T_; kt += 128) {
        TILE_BODY(0, 1, kt);
        TILE_BODY(1, 0, kt + 64);
    }
#undef TILE_BODY
#undef STAGE

    // epilogue: rs_acc holds the full row-sum replicated (no shfl needed)
    for (int g = 0; g < 2; g++) {
        float inv = 1.0f / fmaxf(rs_acc[g][0], 1e-20f);
        size_t orow = base + (size_t)(q0 + wave * 32 + g * 16 + l16) * D_;
        for (int jd = 0; jd < 4; jd++) {
            ushort4 pk;
            pk.x = f2bf(o_acc[g][jd][0] * inv);
            pk.y = f2bf(o_acc[g][jd][1] * inv);
            pk.z = f2bf(o_acc[g][jd][2] * inv);
            pk.w = f2bf(o_acc[g][jd][3] * inv);
            *(ushort4*)(Oout + orow + jd * 16 + quad * 4) = pk;
        }
    }
}

extern "C" void kernel_launch(void* const* d_in, const int* in_sizes, int n_in,
                              void* d_out, int out_size, void* d_ws, size_t ws_size,
                              hipStream_t stream)
{
    const void* x    = d_in[0];
    const u8*   mask = (const u8*)d_in[1];
    const void* wq   = d_in[2];
    const void* bq   = d_in[3];
    const void* wk   = d_in[4];
    const void* bk   = d_in[5];
    const void* wv   = d_in[6];
    const void* bv   = d_in[7];
    const void* wo   = d_in[8];
    const void* bo   = d_in[9];
    const void* lng  = d_in[10];
    const void* lnb  = d_in[11];

    const size_t NTOK = (size_t)B_ * T_;          // 8192
    u16* xn  = (u16*)d_ws;                        // 16.8 MB; reused as attention output
    u16* Kb  = xn + NTOK * D_;                    // 16.8 MB
    u16* Vtb = Kb + NTOK * D_;                    // 16.8 MB (transposed layout)
    u16* wqc = Vtb + NTOK * D_;                   // 2 MB each
    u16* wkc = wqc + (size_t)D_ * D_;
    u16* wvc = wkc + (size_t)D_ * D_;
    u16* woc = wvc + (size_t)D_ * D_;
    u16* vecs = woc + (size_t)D_ * D_;            // 6 x 1024: bq,bk,bv,bo,ln_g,ln_b
    float* msk = (float*)(vecs + 6 * 1024);       // 32 KB float mask bias (0 / -200)
    int* flag = (int*)(msk + 8192);               // dtype flag: 1 = fp32 inputs
    u16* Qb  = (u16*)d_out;                       // Q in d_out (dead until final GEMM)

    mega_prep<<<dim3(12296), 256, 0, stream>>>(
        (const u16*)x, mask, wq, wk, wv, wo, bq, bk, bv, bo, lng, lnb,
        wqc, wkc, wvc, woc, vecs, msk, flag, xn);
    gemm_bt<<<dim3(64, 8, 3), 256, 0, stream>>>(xn, wqc, wkc, wvc, vecs, 0, Qb, Kb, Vtb, 1.0f, flag, 0, 1);
    attn_kernel<<<dim3(64, 16), 256, 0, stream>>>(Qb, Kb, Vtb, msk, xn);
    gemm_bt<<<dim3(64, 8, 1), 256, 0, stream>>>(xn, woc, woc, woc, vecs, 3, (u16*)d_out, (u16*)d_out, (u16*)d_out, 0.5f, flag, 1, 0);
}